// Round 1
// baseline (273.478 us; speedup 1.0000x reference)
//
#include <hip/hip_runtime.h>
#include <hip/hip_bf16.h>

typedef __bf16 bf16x8 __attribute__((ext_vector_type(8)));
typedef float f32x4 __attribute__((ext_vector_type(4)));

#define DEVI __device__ __forceinline__

constexpr int B_ = 2, T_ = 2048, C_ = 1024, H_ = 16, D_ = 64;
constexpr int M_ = B_ * T_;      // 4096 rows
constexpr int K_ = C_;           // 1024 inner dim (both GEMMs)
constexpr int WINDOW_ = 512;
constexpr float SCALE_ = 0.125f; // 1/sqrt(64)

DEVI unsigned short f2bf(float f) {
  unsigned u = __builtin_bit_cast(unsigned, f);
  u += 0x7FFFu + ((u >> 16) & 1u);
  return (unsigned short)(u >> 16);
}

DEVI float softcap30(float x) {
  // 30 * tanh(x / 30)
  float y = x * (1.0f / 30.0f);
  y = fminf(fmaxf(y, -15.0f), 15.0f);
  float t = __expf(2.0f * y);
  return 30.0f * (t - 1.0f) / (t + 1.0f);
}

// ---------------- fp32 -> bf16 conversion (vectorized) ----------------
__global__ void cvt_f32_bf16(const float* __restrict__ in,
                             unsigned short* __restrict__ out, int n4) {
  int i = blockIdx.x * blockDim.x + threadIdx.x;
  if (i >= n4) return;
  float4 v = reinterpret_cast<const float4*>(in)[i];
  ushort4 o;
  o.x = f2bf(v.x); o.y = f2bf(v.y); o.z = f2bf(v.z); o.w = f2bf(v.w);
  reinterpret_cast<ushort4*>(out)[i] = o;
}

// ---------------- bf16 GEMM: out[m,n] = sum_k A[m,k]*W[n,k] + bias[n] -------
// A: [M,1024] row-major bf16. W: [N,1024] row-major bf16 (K-inner, i.e. B^T).
// WHICH==0: QKV epilogue -> q[B,H,T,64], k[B,H,T,64], vt[B,H,64,T] (bf16)
// WHICH==1: proj epilogue -> fp32 out [M, 1024]
template <int WHICH>
__global__ __launch_bounds__(256) void gemm_bt(
    const unsigned short* __restrict__ A, const unsigned short* __restrict__ W,
    const float* __restrict__ bias,
    unsigned short* __restrict__ oq, unsigned short* __restrict__ ok,
    unsigned short* __restrict__ ovt, float* __restrict__ of) {
  constexpr int PS = 40;  // padded LDS row stride (elems): 80B -> ~2-way banks
  __shared__ alignas(16) unsigned short As[128 * PS];
  __shared__ alignas(16) unsigned short Bs[128 * PS];

  const int tid = threadIdx.x;
  const int n0 = blockIdx.x * 128, m0 = blockIdx.y * 128;
  const int lane = tid & 63, w = tid >> 6;
  const int wm = (w >> 1) * 64, wn = (w & 1) * 64;
  const int lr = lane & 15, lg = lane >> 4;

  f32x4 acc[4][4];
#pragma unroll
  for (int i = 0; i < 4; i++)
#pragma unroll
    for (int j = 0; j < 4; j++) acc[i][j] = f32x4{0.f, 0.f, 0.f, 0.f};

  for (int kt = 0; kt < K_; kt += 32) {
#pragma unroll
    for (int i = 0; i < 2; i++) {
      int s = i * 256 + tid;
      int row = s >> 2, seg = (s & 3) * 8;
      *reinterpret_cast<int4*>(&As[row * PS + seg]) =
          *reinterpret_cast<const int4*>(&A[(size_t)(m0 + row) * K_ + kt + seg]);
      *reinterpret_cast<int4*>(&Bs[row * PS + seg]) =
          *reinterpret_cast<const int4*>(&W[(size_t)(n0 + row) * K_ + kt + seg]);
    }
    __syncthreads();
    bf16x8 af[4], bf[4];
#pragma unroll
    for (int m = 0; m < 4; m++)
      af[m] = *reinterpret_cast<const bf16x8*>(&As[(wm + m * 16 + lr) * PS + lg * 8]);
#pragma unroll
    for (int n = 0; n < 4; n++)
      bf[n] = *reinterpret_cast<const bf16x8*>(&Bs[(wn + n * 16 + lr) * PS + lg * 8]);
#pragma unroll
    for (int m = 0; m < 4; m++)
#pragma unroll
      for (int n = 0; n < 4; n++)
        acc[m][n] = __builtin_amdgcn_mfma_f32_16x16x32_bf16(af[m], bf[n], acc[m][n], 0, 0, 0);
    __syncthreads();
  }

#pragma unroll
  for (int ms = 0; ms < 4; ms++) {
#pragma unroll
    for (int ns = 0; ns < 4; ns++) {
#pragma unroll
      for (int r = 0; r < 4; r++) {
        int m = m0 + wm + ms * 16 + lg * 4 + r;
        int n = n0 + wn + ns * 16 + lr;
        float v = acc[ms][ns][r] + bias[n];
        if constexpr (WHICH == 0) {
          int part = n >> 10, nc = n & 1023;
          int hh = nc >> 6, dd = nc & 63;
          int bb = m >> 11, tt = m & 2047;
          unsigned short bv = f2bf(v);
          if (part == 0)
            oq[(((size_t)(bb * H_ + hh)) * T_ + tt) * D_ + dd] = bv;
          else if (part == 1)
            ok[(((size_t)(bb * H_ + hh)) * T_ + tt) * D_ + dd] = bv;
          else
            ovt[(((size_t)(bb * H_ + hh)) * D_ + dd) * T_ + tt] = bv;
        } else {
          of[(size_t)m * C_ + n] = v;
        }
      }
    }
  }
}

// ---------------- flash attention: window-causal + global prefix + softcap ---
// q,k: [B,H,T,64] bf16; vt: [B,H,64,T] bf16; out: [B*T, C] bf16
__global__ __launch_bounds__(64) void attn_fwd(
    const unsigned short* __restrict__ qg, const unsigned short* __restrict__ kg,
    const unsigned short* __restrict__ vtg, const int* __restrict__ spl_arr,
    unsigned short* __restrict__ out) {
  const int l = threadIdx.x, lr = l & 15, lg = l >> 4;
  const int qb = blockIdx.x, h = blockIdx.y, b = blockIdx.z;
  const int i0 = qb * 16;
  const int spl = spl_arr[b];
  const size_t bh = (size_t)(b * H_ + h);
  const unsigned short* qp = qg + bh * T_ * D_;
  const unsigned short* kp = kg + bh * T_ * D_;
  const unsigned short* vp = vtg + bh * (size_t)D_ * T_;

  __shared__ alignas(16) unsigned short P[16 * 40];

  bf16x8 aq0 = *reinterpret_cast<const bf16x8*>(qp + (size_t)(i0 + lr) * D_ + lg * 8);
  bf16x8 aq1 = *reinterpret_cast<const bf16x8*>(qp + (size_t)(i0 + lr) * D_ + 32 + lg * 8);

  float mr[4], lsum[4];
  f32x4 acc[4];
#pragma unroll
  for (int r = 0; r < 4; r++) { mr[r] = -1e30f; lsum[r] = 0.f; }
#pragma unroll
  for (int nb = 0; nb < 4; nb++) acc[nb] = f32x4{0.f, 0.f, 0.f, 0.f};

  const int lo2 = i0 > WINDOW_ ? i0 - WINDOW_ : 0;
  const int lo2b = lo2 & ~31;
  const int end1 = (spl + 31) & ~31;        // first KV block not in prefix loop
  const int start2 = lo2b > end1 ? lo2b : end1;
  const int hi = i0 + 15;
  const int nb1 = (spl + 31) >> 5;
  const int nb2 = (start2 <= hi) ? (((hi - start2) >> 5) + 1) : 0;
  const int ntot = nb1 + nb2;

  for (int tb = 0; tb < ntot; tb++) {
    const int j0 = (tb < nb1) ? tb * 32 : start2 + (tb - nb1) * 32;
    const unsigned short* kb = kp + (size_t)j0 * D_;

    bf16x8 bk00 = *reinterpret_cast<const bf16x8*>(kb + (size_t)lr * 64 + lg * 8);
    bf16x8 bk01 = *reinterpret_cast<const bf16x8*>(kb + (size_t)lr * 64 + 32 + lg * 8);
    bf16x8 bk10 = *reinterpret_cast<const bf16x8*>(kb + (size_t)(16 + lr) * 64 + lg * 8);
    bf16x8 bk11 = *reinterpret_cast<const bf16x8*>(kb + (size_t)(16 + lr) * 64 + 32 + lg * 8);

    f32x4 s0 = f32x4{0.f, 0.f, 0.f, 0.f}, s1 = f32x4{0.f, 0.f, 0.f, 0.f};
    s0 = __builtin_amdgcn_mfma_f32_16x16x32_bf16(aq0, bk00, s0, 0, 0, 0);
    s0 = __builtin_amdgcn_mfma_f32_16x16x32_bf16(aq1, bk01, s0, 0, 0, 0);
    s1 = __builtin_amdgcn_mfma_f32_16x16x32_bf16(aq0, bk10, s1, 0, 0, 0);
    s1 = __builtin_amdgcn_mfma_f32_16x16x32_bf16(aq1, bk11, s1, 0, 0, 0);

    float p0[4], p1[4], cf[4];
    const int jc0 = j0 + lr, jc1 = j0 + 16 + lr;
#pragma unroll
    for (int r = 0; r < 4; r++) {
      const int irow = i0 + lg * 4 + r;
      float x0 = softcap30(s0[r] * SCALE_);
      float x1 = softcap30(s1[r] * SCALE_);
      bool v0 = (jc0 <= irow && irow - jc0 <= WINDOW_) || (jc0 < spl);
      bool v1 = (jc1 <= irow && irow - jc1 <= WINDOW_) || (jc1 < spl);
      x0 = v0 ? x0 : -1e30f;
      x1 = v1 ? x1 : -1e30f;
      float rm = fmaxf(x0, x1);
      rm = fmaxf(rm, __shfl_xor(rm, 1));
      rm = fmaxf(rm, __shfl_xor(rm, 2));
      rm = fmaxf(rm, __shfl_xor(rm, 4));
      rm = fmaxf(rm, __shfl_xor(rm, 8));
      float mn = fmaxf(mr[r], rm);
      float c = __expf(mr[r] - mn);
      p0[r] = __expf(x0 - mn);
      p1[r] = __expf(x1 - mn);
      float rs = p0[r] + p1[r];
      rs += __shfl_xor(rs, 1);
      rs += __shfl_xor(rs, 2);
      rs += __shfl_xor(rs, 4);
      rs += __shfl_xor(rs, 8);
      lsum[r] = lsum[r] * c + rs;
      mr[r] = mn;
      cf[r] = c;
    }
#pragma unroll
    for (int nb = 0; nb < 4; nb++) {
#pragma unroll
      for (int r = 0; r < 4; r++) acc[nb][r] *= cf[r];
    }
#pragma unroll
    for (int r = 0; r < 4; r++) {
      P[(lg * 4 + r) * 40 + lr] = f2bf(p0[r]);
      P[(lg * 4 + r) * 40 + 16 + lr] = f2bf(p1[r]);
    }
    __syncthreads();
    bf16x8 pa = *reinterpret_cast<const bf16x8*>(&P[lr * 40 + lg * 8]);
#pragma unroll
    for (int nb = 0; nb < 4; nb++) {
      bf16x8 bv = *reinterpret_cast<const bf16x8*>(vp + (size_t)(nb * 16 + lr) * T_ + j0 + lg * 8);
      acc[nb] = __builtin_amdgcn_mfma_f32_16x16x32_bf16(pa, bv, acc[nb], 0, 0, 0);
    }
    __syncthreads();
  }

#pragma unroll
  for (int nb = 0; nb < 4; nb++) {
#pragma unroll
    for (int r = 0; r < 4; r++) {
      float o = acc[nb][r] / lsum[r];
      int t = i0 + lg * 4 + r;
      out[((size_t)(b * T_ + t)) * C_ + h * D_ + nb * 16 + lr] = f2bf(o);
    }
  }
}

extern "C" void kernel_launch(void* const* d_in, const int* in_sizes, int n_in,
                              void* d_out, int out_size, void* d_ws, size_t ws_size,
                              hipStream_t stream) {
  const float* x = (const float*)d_in[0];
  const int* spl = (const int*)d_in[1];
  const float* Wqkv = (const float*)d_in[2];
  const float* bqkv = (const float*)d_in[3];
  const float* Wproj = (const float*)d_in[4];
  const float* bproj = (const float*)d_in[5];
  float* out = (float*)d_out;

  char* ws = (char*)d_ws;
  unsigned short* xb = (unsigned short*)ws;       ws += (size_t)M_ * K_ * 2;        // 8 MB
  unsigned short* wqkvb = (unsigned short*)ws;    ws += (size_t)3 * C_ * K_ * 2;    // 6 MB
  unsigned short* wprojb = (unsigned short*)ws;   ws += (size_t)C_ * K_ * 2;        // 2 MB
  unsigned short* qb = (unsigned short*)ws;       ws += (size_t)M_ * C_ * 2;        // 8 MB
  unsigned short* kb = (unsigned short*)ws;       ws += (size_t)M_ * C_ * 2;        // 8 MB
  unsigned short* vtb = (unsigned short*)ws;      ws += (size_t)M_ * C_ * 2;        // 8 MB
  unsigned short* ab = (unsigned short*)ws;       ws += (size_t)M_ * C_ * 2;        // 8 MB

  {
    int n4 = (M_ * K_) / 4;
    cvt_f32_bf16<<<(n4 + 255) / 256, 256, 0, stream>>>(x, xb, n4);
  }
  {
    int n4 = (3 * C_ * K_) / 4;
    cvt_f32_bf16<<<(n4 + 255) / 256, 256, 0, stream>>>(Wqkv, wqkvb, n4);
  }
  {
    int n4 = (C_ * K_) / 4;
    cvt_f32_bf16<<<(n4 + 255) / 256, 256, 0, stream>>>(Wproj, wprojb, n4);
  }

  gemm_bt<0><<<dim3(3 * C_ / 128, M_ / 128), 256, 0, stream>>>(
      xb, wqkvb, bqkv, qb, kb, vtb, nullptr);

  attn_fwd<<<dim3(T_ / 16, H_, B_), 64, 0, stream>>>(qb, kb, vtb, spl, ab);

  gemm_bt<1><<<dim3(C_ / 128, M_ / 128), 256, 0, stream>>>(
      ab, wprojb, bproj, nullptr, nullptr, nullptr, out);
}

// Round 3
// 222.795 us; speedup vs baseline: 1.2275x; 1.2275x over previous
//
#include <hip/hip_runtime.h>
#include <hip/hip_bf16.h>

typedef __bf16 bf16x8 __attribute__((ext_vector_type(8)));
typedef float f32x4 __attribute__((ext_vector_type(4)));

#define DEVI __device__ __forceinline__

constexpr int B_ = 2, T_ = 2048, C_ = 1024, H_ = 16, D_ = 64;
constexpr int M_ = B_ * T_;      // 4096 rows
constexpr int K_ = C_;           // 1024 inner dim (both GEMMs)
constexpr int WINDOW_ = 512;
constexpr float SCALE_ = 0.125f; // 1/sqrt(64)

DEVI unsigned short f2bf(float f) {
  unsigned u = __builtin_bit_cast(unsigned, f);
  u += 0x7FFFu + ((u >> 16) & 1u);
  return (unsigned short)(u >> 16);
}

DEVI float softcap30(float x) {
  // 30 * tanh(x / 30)
  float y = x * (1.0f / 30.0f);
  y = fminf(fmaxf(y, -15.0f), 15.0f);
  float t = __expf(2.0f * y);
  return 30.0f * (t - 1.0f) / (t + 1.0f);
}

DEVI void gl_lds16(const unsigned short* g, unsigned short* l) {
  __builtin_amdgcn_global_load_lds(
      (const __attribute__((address_space(1))) unsigned int*)g,
      (__attribute__((address_space(3))) unsigned int*)l, 16, 0, 0);
}

// ---------------- fp32 -> bf16 conversion (vectorized) ----------------
__global__ void cvt_f32_bf16(const float* __restrict__ in,
                             unsigned short* __restrict__ out, int n4) {
  int i = blockIdx.x * blockDim.x + threadIdx.x;
  if (i >= n4) return;
  float4 v = reinterpret_cast<const float4*>(in)[i];
  ushort4 o;
  o.x = f2bf(v.x); o.y = f2bf(v.y); o.z = f2bf(v.z); o.w = f2bf(v.w);
  reinterpret_cast<ushort4*>(out)[i] = o;
}

// ---------------- bf16 GEMM: acc[m,n] = sum_k A[m,k]*W[n,k] ----------------
// m97 structure: global_load_lds width-16 staging, linear LDS, BK=32, 128^2.
// WHICH==0: A=x, W=W_qk (N=2048) -> q[B,H,T,64], k[B,H,T,64] bf16
// WHICH==1: A=att, W=W_proj       -> fp32 out [M, C]
// WHICH==2: A=W_v (M=1024), W=x (N=4096) -> vt[B,H,64,T] bf16 (bias over m!)
template <int WHICH>
__global__ __launch_bounds__(256) void gemm_bt(
    const unsigned short* __restrict__ A, const unsigned short* __restrict__ W,
    const float* __restrict__ bias,
    unsigned short* __restrict__ oq, unsigned short* __restrict__ ok,
    unsigned short* __restrict__ ovt, float* __restrict__ of) {
  __shared__ alignas(16) unsigned short As[128 * 32];
  __shared__ alignas(16) unsigned short Bs[128 * 32];

  const int tid = threadIdx.x;
  const int n0 = blockIdx.x * 128, m0 = blockIdx.y * 128;
  const int lane = tid & 63, w = tid >> 6;
  const int wm = (w >> 1) * 64, wn = (w & 1) * 64;
  const int lr = lane & 15, lg = lane >> 4;
  const int srow = lane >> 2, scs = (lane & 3) << 3;  // staging: row-in-16, col-seg

  f32x4 acc[4][4];
#pragma unroll
  for (int i = 0; i < 4; i++)
#pragma unroll
    for (int j = 0; j < 4; j++) acc[i][j] = f32x4{0.f, 0.f, 0.f, 0.f};

  for (int kt = 0; kt < K_; kt += 32) {
#pragma unroll
    for (int i = 0; i < 2; i++) {
      const int rb = i * 64 + w * 16;  // wave-uniform base row
      gl_lds16(&A[(size_t)(m0 + rb + srow) * K_ + kt + scs], &As[rb * 32]);
      gl_lds16(&W[(size_t)(n0 + rb + srow) * K_ + kt + scs], &Bs[rb * 32]);
    }
    __syncthreads();
    bf16x8 af[4], bf[4];
#pragma unroll
    for (int m = 0; m < 4; m++)
      af[m] = *reinterpret_cast<const bf16x8*>(&As[(wm + m * 16 + lr) * 32 + lg * 8]);
#pragma unroll
    for (int n = 0; n < 4; n++)
      bf[n] = *reinterpret_cast<const bf16x8*>(&Bs[(wn + n * 16 + lr) * 32 + lg * 8]);
#pragma unroll
    for (int m = 0; m < 4; m++)
#pragma unroll
      for (int n = 0; n < 4; n++)
        acc[m][n] = __builtin_amdgcn_mfma_f32_16x16x32_bf16(af[m], bf[n], acc[m][n], 0, 0, 0);
    __syncthreads();
  }

#pragma unroll
  for (int ms = 0; ms < 4; ms++) {
#pragma unroll
    for (int ns = 0; ns < 4; ns++) {
#pragma unroll
      for (int r = 0; r < 4; r++) {
        int m = m0 + wm + ms * 16 + lg * 4 + r;
        int n = n0 + wn + ns * 16 + lr;
        if constexpr (WHICH == 0) {
          float v = acc[ms][ns][r] + bias[n];
          int part = n >> 10, nc = n & 1023;
          int hh = nc >> 6, dd = nc & 63;
          int bb = m >> 11, tt = m & 2047;
          unsigned short bv = f2bf(v);
          if (part == 0)
            oq[(((size_t)(bb * H_ + hh)) * T_ + tt) * D_ + dd] = bv;
          else
            ok[(((size_t)(bb * H_ + hh)) * T_ + tt) * D_ + dd] = bv;
        } else if constexpr (WHICH == 1) {
          of[(size_t)m * C_ + n] = acc[ms][ns][r] + bias[n];
        } else {
          // m = v-channel (h*64+dd), n = token (b*2048+tt); bias indexed by m
          float v = acc[ms][ns][r] + bias[m];
          int hh = m >> 6, dd = m & 63;
          int bb = n >> 11, tt = n & 2047;
          ovt[(((size_t)(bb * H_ + hh)) * D_ + dd) * T_ + tt] = f2bf(v);
        }
      }
    }
  }
}

// ---------------- flash attention: window-causal + global prefix + softcap ---
// q,k: [B,H,T,64] bf16; vt: [B,H,64,T] bf16; out: [B*T, C] bf16
// 4 waves/block, 64-query tile, KVBLK=64 staged in XOR-swizzled LDS.
__global__ __launch_bounds__(256) void attn_fwd(
    const unsigned short* __restrict__ qg, const unsigned short* __restrict__ kg,
    const unsigned short* __restrict__ vtg, const int* __restrict__ spl_arr,
    unsigned short* __restrict__ out) {
  const int tid = threadIdx.x;
  const int l = tid & 63, w = tid >> 6;
  const int lr = l & 15, lg = l >> 4;

  // XCD swizzle: all 32 q-tiles of one (b,h) share l%8 => same XCD.
  const int lin = blockIdx.x;             // 0..1023
  const int xs = lin & 7, slot = lin >> 3;
  const int g = xs + 8 * (slot >> 5);     // bh group 0..31
  const int iblk = slot & 31;             // q tile 0..31
  const int b = g >> 4, h = g & 15;
  const int q_base = iblk * 64;
  const int i0 = q_base + w * 16;         // this wave's 16 query rows

  const int spl = spl_arr[b];
  const size_t bh = (size_t)(b * H_ + h);
  const unsigned short* qp = qg + bh * T_ * D_;
  const unsigned short* kp = kg + bh * T_ * D_;
  const unsigned short* vp = vtg + bh * (size_t)D_ * T_;

  __shared__ alignas(16) unsigned short Ks[64 * 64];      // [kv][d], swizzled
  __shared__ alignas(16) unsigned short Vs[64 * 64];      // [d][kv], swizzled
  __shared__ alignas(16) unsigned short Ps[4][16][72];    // per-wave P, padded

  bf16x8 aq0 = *reinterpret_cast<const bf16x8*>(qp + (size_t)(i0 + lr) * D_ + lg * 8);
  bf16x8 aq1 = *reinterpret_cast<const bf16x8*>(qp + (size_t)(i0 + lr) * D_ + 32 + lg * 8);

  float mr[4], lsum[4];
  f32x4 acc[4];
#pragma unroll
  for (int r = 0; r < 4; r++) { mr[r] = -1e30f; lsum[r] = 0.f; }
#pragma unroll
  for (int nb = 0; nb < 4; nb++) acc[nb] = f32x4{0.f, 0.f, 0.f, 0.f};

  // tile schedule (block-level, union over 4 waves)
  const int pref_tiles = (spl + 63) >> 6;
  const int pref_end = pref_tiles << 6;
  int wl = q_base - WINDOW_; if (wl < 0) wl = 0; wl &= ~63;
  const int start2 = wl > pref_end ? wl : pref_end;
  const int hi = q_base + 63;
  const int n2 = (start2 <= hi) ? (((hi - start2) >> 6) + 1) : 0;
  const int ntot = pref_tiles + n2;

  // staging indices: 256 threads, 32B per thread for each of K and V
  const int strow = tid >> 2;              // 0..63 (row)
  const int c0 = (tid & 3) << 4;           // col segment base: 0,16,32,48 elems
  const int ssw = (strow & 7) << 3;        // XOR swizzle (8-elem units)

  for (int tb = 0; tb < ntot; tb++) {
    const int j0 = (tb < pref_tiles) ? (tb << 6) : (start2 + ((tb - pref_tiles) << 6));
    {
      const unsigned short* krow = kp + (size_t)(j0 + strow) * D_;
      const unsigned short* vrow = vp + (size_t)strow * T_ + j0;
      int4 ka0 = *reinterpret_cast<const int4*>(krow + c0);
      int4 ka1 = *reinterpret_cast<const int4*>(krow + c0 + 8);
      int4 va0 = *reinterpret_cast<const int4*>(vrow + c0);
      int4 va1 = *reinterpret_cast<const int4*>(vrow + c0 + 8);
      *reinterpret_cast<int4*>(&Ks[strow * 64 + (c0 ^ ssw)]) = ka0;
      *reinterpret_cast<int4*>(&Ks[strow * 64 + ((c0 + 8) ^ ssw)]) = ka1;
      *reinterpret_cast<int4*>(&Vs[strow * 64 + (c0 ^ ssw)]) = va0;
      *reinterpret_cast<int4*>(&Vs[strow * 64 + ((c0 + 8) ^ ssw)]) = va1;
    }
    __syncthreads();

    const bool rel = (j0 < spl) || (j0 + 63 >= i0 - WINDOW_ && j0 <= i0 + 15);
    if (rel) {
      // QK^T: S[16 q][64 kv] as 4 sub-tiles
      f32x4 s[4];
#pragma unroll
      for (int ks = 0; ks < 4; ks++) {
        const int krow = ks * 16 + lr;
        const int sw = (krow & 7) << 3;
        bf16x8 b0 = *reinterpret_cast<const bf16x8*>(&Ks[krow * 64 + ((lg * 8) ^ sw)]);
        bf16x8 b1 = *reinterpret_cast<const bf16x8*>(&Ks[krow * 64 + ((32 + lg * 8) ^ sw)]);
        f32x4 t = f32x4{0.f, 0.f, 0.f, 0.f};
        t = __builtin_amdgcn_mfma_f32_16x16x32_bf16(aq0, b0, t, 0, 0, 0);
        s[ks] = __builtin_amdgcn_mfma_f32_16x16x32_bf16(aq1, b1, t, 0, 0, 0);
      }
      // online softmax, rows owned by (lg, r)
      float cf[4];
#pragma unroll
      for (int r = 0; r < 4; r++) {
        const int irow = i0 + lg * 4 + r;
        float xv[4];
#pragma unroll
        for (int ks = 0; ks < 4; ks++) {
          const int jc = j0 + ks * 16 + lr;
          float xsc = softcap30(s[ks][r] * SCALE_);
          bool valid = (jc <= irow && irow - jc <= WINDOW_) || (jc < spl);
          xv[ks] = valid ? xsc : -1e30f;
        }
        float rm = fmaxf(fmaxf(xv[0], xv[1]), fmaxf(xv[2], xv[3]));
        rm = fmaxf(rm, __shfl_xor(rm, 1));
        rm = fmaxf(rm, __shfl_xor(rm, 2));
        rm = fmaxf(rm, __shfl_xor(rm, 4));
        rm = fmaxf(rm, __shfl_xor(rm, 8));
        const float mn = fmaxf(mr[r], rm);
        const float c = __expf(mr[r] - mn);
        float ps0 = __expf(xv[0] - mn), ps1 = __expf(xv[1] - mn);
        float ps2 = __expf(xv[2] - mn), ps3 = __expf(xv[3] - mn);
        float rs = (ps0 + ps1) + (ps2 + ps3);
        rs += __shfl_xor(rs, 1);
        rs += __shfl_xor(rs, 2);
        rs += __shfl_xor(rs, 4);
        rs += __shfl_xor(rs, 8);
        lsum[r] = lsum[r] * c + rs;
        mr[r] = mn;
        cf[r] = c;
        const int prow = lg * 4 + r;
        Ps[w][prow][lr] = f2bf(ps0);
        Ps[w][prow][16 + lr] = f2bf(ps1);
        Ps[w][prow][32 + lr] = f2bf(ps2);
        Ps[w][prow][48 + lr] = f2bf(ps3);
      }
#pragma unroll
      for (int nb = 0; nb < 4; nb++)
#pragma unroll
        for (int r = 0; r < 4; r++) acc[nb][r] *= cf[r];

      // ensure this wave's cross-lane P writes have landed in LDS
      asm volatile("s_waitcnt lgkmcnt(0)" ::: "memory");

      bf16x8 pa0 = *reinterpret_cast<const bf16x8*>(&Ps[w][lr][lg * 8]);
      bf16x8 pa1 = *reinterpret_cast<const bf16x8*>(&Ps[w][lr][32 + lg * 8]);
#pragma unroll
      for (int nb = 0; nb < 4; nb++) {
        const int vrow = nb * 16 + lr;
        const int sw = (vrow & 7) << 3;
        bf16x8 bv0 = *reinterpret_cast<const bf16x8*>(&Vs[vrow * 64 + ((lg * 8) ^ sw)]);
        bf16x8 bv1 = *reinterpret_cast<const bf16x8*>(&Vs[vrow * 64 + ((32 + lg * 8) ^ sw)]);
        acc[nb] = __builtin_amdgcn_mfma_f32_16x16x32_bf16(pa0, bv0, acc[nb], 0, 0, 0);
        acc[nb] = __builtin_amdgcn_mfma_f32_16x16x32_bf16(pa1, bv1, acc[nb], 0, 0, 0);
      }
    }
    __syncthreads();
  }

#pragma unroll
  for (int nb = 0; nb < 4; nb++) {
#pragma unroll
    for (int r = 0; r < 4; r++) {
      float o = acc[nb][r] / lsum[r];
      int t = i0 + lg * 4 + r;
      out[((size_t)(b * T_ + t)) * C_ + h * D_ + nb * 16 + lr] = f2bf(o);
    }
  }
}

extern "C" void kernel_launch(void* const* d_in, const int* in_sizes, int n_in,
                              void* d_out, int out_size, void* d_ws, size_t ws_size,
                              hipStream_t stream) {
  const float* x = (const float*)d_in[0];
  const int* spl = (const int*)d_in[1];
  const float* Wqkv = (const float*)d_in[2];
  const float* bqkv = (const float*)d_in[3];
  const float* Wproj = (const float*)d_in[4];
  const float* bproj = (const float*)d_in[5];
  float* out = (float*)d_out;

  char* ws = (char*)d_ws;
  unsigned short* xb = (unsigned short*)ws;       ws += (size_t)M_ * K_ * 2;        // 8 MB
  unsigned short* wqkvb = (unsigned short*)ws;    ws += (size_t)3 * C_ * K_ * 2;    // 6 MB
  unsigned short* wprojb = (unsigned short*)ws;   ws += (size_t)C_ * K_ * 2;        // 2 MB
  unsigned short* qb = (unsigned short*)ws;       ws += (size_t)M_ * C_ * 2;        // 8 MB
  unsigned short* kb = (unsigned short*)ws;       ws += (size_t)M_ * C_ * 2;        // 8 MB
  unsigned short* vtb = (unsigned short*)ws;      ws += (size_t)M_ * C_ * 2;        // 8 MB
  unsigned short* ab = (unsigned short*)ws;       ws += (size_t)M_ * C_ * 2;        // 8 MB

  {
    int n4 = (M_ * K_) / 4;
    cvt_f32_bf16<<<(n4 + 255) / 256, 256, 0, stream>>>(x, xb, n4);
  }
  {
    int n4 = (3 * C_ * K_) / 4;
    cvt_f32_bf16<<<(n4 + 255) / 256, 256, 0, stream>>>(Wqkv, wqkvb, n4);
  }
  {
    int n4 = (C_ * K_) / 4;
    cvt_f32_bf16<<<(n4 + 255) / 256, 256, 0, stream>>>(Wproj, wprojb, n4);
  }

  // QK projection: N=2048 (first 2048 rows of W_qkv)
  gemm_bt<0><<<dim3(2048 / 128, M_ / 128), 256, 0, stream>>>(
      xb, wqkvb, bqkv, qb, kb, nullptr, nullptr);

  // V projection, swapped: A = W_v (1024 rows), B = x (4096 rows) -> vt[B,H,64,T]
  gemm_bt<2><<<dim3(M_ / 128, 1024 / 128), 256, 0, stream>>>(
      wqkvb + (size_t)2048 * K_, xb, bqkv + 2048, nullptr, nullptr, vtb, nullptr);

  attn_fwd<<<dim3(1024), 256, 0, stream>>>(qb, kb, vtb, spl, ab);

  gemm_bt<1><<<dim3(C_ / 128, M_ / 128), 256, 0, stream>>>(
      ab, wprojb, bproj, nullptr, nullptr, nullptr, out);
}

// Round 5
// 191.040 us; speedup vs baseline: 1.4315x; 1.1662x over previous
//
#include <hip/hip_runtime.h>
#include <hip/hip_bf16.h>

typedef __bf16 bf16x8 __attribute__((ext_vector_type(8)));
typedef float f32x4 __attribute__((ext_vector_type(4)));

#define DEVI __device__ __forceinline__

constexpr int B_ = 2, T_ = 2048, C_ = 1024, H_ = 16, D_ = 64;
constexpr int M_ = B_ * T_;      // 4096 rows
constexpr int K_ = C_;           // 1024 inner dim (both GEMMs)
constexpr int WINDOW_ = 512;
constexpr float SCALE_ = 0.125f; // 1/sqrt(64)

DEVI unsigned short f2bf(float f) {
  return __builtin_bit_cast(unsigned short, (__bf16)f);  // RNE, 1 VALU op
}

DEVI void gl_lds16(const unsigned short* g, unsigned short* l) {
  __builtin_amdgcn_global_load_lds(
      (const __attribute__((address_space(1))) unsigned int*)g,
      (__attribute__((address_space(3))) unsigned int*)l, 16, 0, 0);
}

// ---------------- fp32 -> bf16 conversion (vectorized) ----------------
__global__ void cvt_f32_bf16(const float* __restrict__ in,
                             unsigned short* __restrict__ out, int n4) {
  int i = blockIdx.x * blockDim.x + threadIdx.x;
  if (i >= n4) return;
  float4 v = reinterpret_cast<const float4*>(in)[i];
  ushort4 o;
  o.x = f2bf(v.x); o.y = f2bf(v.y); o.z = f2bf(v.z); o.w = f2bf(v.w);
  reinterpret_cast<ushort4*>(out)[i] = o;
}

// ---------------- bf16 GEMM: acc[m,n] = sum_k A[m,k]*W[n,k] ----------------
// m97 structure: global_load_lds width-16 staging, linear LDS, BK=32, 128^2.
// WHICH==0: A=x, W=W_qk (N=2048) -> q[B,H,T,64], k[B,H,T,64] bf16
// WHICH==1: A=att, W=W_proj       -> fp32 out [M, C]
// WHICH==2: A=W_v (M=1024), W=x (N=4096) -> vt[B,H,64,T] bf16 (bias over m!)
template <int WHICH>
__global__ __launch_bounds__(256) void gemm_bt(
    const unsigned short* __restrict__ A, const unsigned short* __restrict__ W,
    const float* __restrict__ bias,
    unsigned short* __restrict__ oq, unsigned short* __restrict__ ok,
    unsigned short* __restrict__ ovt, float* __restrict__ of) {
  __shared__ alignas(16) unsigned short As[128 * 32];
  __shared__ alignas(16) unsigned short Bs[128 * 32];

  const int tid = threadIdx.x;
  const int n0 = blockIdx.x * 128, m0 = blockIdx.y * 128;
  const int lane = tid & 63, w = tid >> 6;
  const int wm = (w >> 1) * 64, wn = (w & 1) * 64;
  const int lr = lane & 15, lg = lane >> 4;
  const int srow = lane >> 2, scs = (lane & 3) << 3;  // staging: row-in-16, col-seg

  f32x4 acc[4][4];
#pragma unroll
  for (int i = 0; i < 4; i++)
#pragma unroll
    for (int j = 0; j < 4; j++) acc[i][j] = f32x4{0.f, 0.f, 0.f, 0.f};

  for (int kt = 0; kt < K_; kt += 32) {
#pragma unroll
    for (int i = 0; i < 2; i++) {
      const int rb = i * 64 + w * 16;  // wave-uniform base row
      gl_lds16(&A[(size_t)(m0 + rb + srow) * K_ + kt + scs], &As[rb * 32]);
      gl_lds16(&W[(size_t)(n0 + rb + srow) * K_ + kt + scs], &Bs[rb * 32]);
    }
    __syncthreads();
    bf16x8 af[4], bf[4];
#pragma unroll
    for (int m = 0; m < 4; m++)
      af[m] = *reinterpret_cast<const bf16x8*>(&As[(wm + m * 16 + lr) * 32 + lg * 8]);
#pragma unroll
    for (int n = 0; n < 4; n++)
      bf[n] = *reinterpret_cast<const bf16x8*>(&Bs[(wn + n * 16 + lr) * 32 + lg * 8]);
#pragma unroll
    for (int m = 0; m < 4; m++)
#pragma unroll
      for (int n = 0; n < 4; n++)
        acc[m][n] = __builtin_amdgcn_mfma_f32_16x16x32_bf16(af[m], bf[n], acc[m][n], 0, 0, 0);
    __syncthreads();
  }

#pragma unroll
  for (int ms = 0; ms < 4; ms++) {
#pragma unroll
    for (int ns = 0; ns < 4; ns++) {
#pragma unroll
      for (int r = 0; r < 4; r++) {
        int m = m0 + wm + ms * 16 + lg * 4 + r;
        int n = n0 + wn + ns * 16 + lr;
        if constexpr (WHICH == 0) {
          float v = acc[ms][ns][r] + bias[n];
          int part = n >> 10, nc = n & 1023;
          int hh = nc >> 6, dd = nc & 63;
          int bb = m >> 11, tt = m & 2047;
          unsigned short bv = f2bf(v);
          if (part == 0)
            oq[(((size_t)(bb * H_ + hh)) * T_ + tt) * D_ + dd] = bv;
          else
            ok[(((size_t)(bb * H_ + hh)) * T_ + tt) * D_ + dd] = bv;
        } else if constexpr (WHICH == 1) {
          of[(size_t)m * C_ + n] = acc[ms][ns][r] + bias[n];
        } else {
          // m = v-channel (h*64+dd), n = token (b*2048+tt); bias indexed by m
          float v = acc[ms][ns][r] + bias[m];
          int hh = m >> 6, dd = m & 63;
          int bb = n >> 11, tt = n & 2047;
          ovt[(((size_t)(bb * H_ + hh)) * D_ + dd) * T_ + tt] = f2bf(v);
        }
      }
    }
  }
}

// ---------------- flash attention: window-causal + global prefix + softcap ---
// q,k: [B,H,T,64] bf16; vt: [B,H,64,T] bf16; out: [B*T, C] bf16
// 4 waves/block, 64-query tile, KVBLK=64 staged in XOR-swizzled LDS.
// Fixed-max softmax: scores softcapped to [-30,30] => use M=30 always.
// p = exp(score-30) = exp2(C3 * rcp(1 + exp2(C1*s))), s = raw qk dot.
__global__ __launch_bounds__(256) void attn_fwd(
    const unsigned short* __restrict__ qg, const unsigned short* __restrict__ kg,
    const unsigned short* __restrict__ vtg, const int* __restrict__ spl_arr,
    unsigned short* __restrict__ out) {
  const int tid = threadIdx.x;
  const int l = tid & 63, w = tid >> 6;
  const int lr = l & 15, lg = l >> 4;

  constexpr float C1 = 0.012022458674074695f;  // SCALE * log2(e) / 15
  constexpr float C3 = -86.56170245333781f;    // -60 * log2(e)

  // XCD swizzle: all 32 q-tiles of one (b,h) share l%8 => same XCD.
  const int lin = blockIdx.x;             // 0..1023
  const int xs = lin & 7, slot = lin >> 3;
  const int g = xs + 8 * (slot >> 5);     // bh group 0..31
  const int iblk = slot & 31;             // q tile 0..31
  const int b = g >> 4, h = g & 15;
  const int q_base = iblk * 64;
  const int i0 = q_base + w * 16;         // this wave's 16 query rows

  const int spl = spl_arr[b];
  const size_t bh = (size_t)(b * H_ + h);
  const unsigned short* qp = qg + bh * T_ * D_;
  const unsigned short* kp = kg + bh * T_ * D_;
  const unsigned short* vp = vtg + bh * (size_t)D_ * T_;

  __shared__ alignas(16) unsigned short Ks[64 * 64];      // [kv][d], swizzled
  __shared__ alignas(16) unsigned short Vs[64 * 64];      // [d][kv], swizzled
  __shared__ alignas(16) unsigned short Ps[4][16][80];    // per-wave P, stride 80

  bf16x8 aq0 = *reinterpret_cast<const bf16x8*>(qp + (size_t)(i0 + lr) * D_ + lg * 8);
  bf16x8 aq1 = *reinterpret_cast<const bf16x8*>(qp + (size_t)(i0 + lr) * D_ + 32 + lg * 8);

  const unsigned short one_bf = 0x3F80;
  bf16x8 ONES;
#pragma unroll
  for (int i = 0; i < 8; i++) ONES[i] = __builtin_bit_cast(__bf16, one_bf);

  f32x4 acc[4];
  f32x4 accl = f32x4{0.f, 0.f, 0.f, 0.f};
#pragma unroll
  for (int nb = 0; nb < 4; nb++) acc[nb] = f32x4{0.f, 0.f, 0.f, 0.f};

  // tile schedule (block-level, union over 4 waves)
  const int pref_tiles = (spl + 63) >> 6;
  const int pref_end = pref_tiles << 6;
  int wl = q_base - WINDOW_; if (wl < 0) wl = 0; wl &= ~63;
  const int start2 = wl > pref_end ? wl : pref_end;
  const int hi = q_base + 63;
  const int n2 = (start2 <= hi) ? (((hi - start2) >> 6) + 1) : 0;
  const int ntot = pref_tiles + n2;

  // staging indices: 256 threads, 32B per thread for each of K and V
  const int strow = tid >> 2;              // 0..63 (row)
  const int c0 = (tid & 3) << 4;           // col segment base: 0,16,32,48 elems
  const int ssw = (strow & 7) << 3;        // XOR swizzle (8-elem units)

  for (int tb = 0; tb < ntot; tb++) {
    const int j0 = (tb < pref_tiles) ? (tb << 6) : (start2 + ((tb - pref_tiles) << 6));
    {
      const unsigned short* krow = kp + (size_t)(j0 + strow) * D_;
      const unsigned short* vrow = vp + (size_t)strow * T_ + j0;
      int4 ka0 = *reinterpret_cast<const int4*>(krow + c0);
      int4 ka1 = *reinterpret_cast<const int4*>(krow + c0 + 8);
      int4 va0 = *reinterpret_cast<const int4*>(vrow + c0);
      int4 va1 = *reinterpret_cast<const int4*>(vrow + c0 + 8);
      *reinterpret_cast<int4*>(&Ks[strow * 64 + (c0 ^ ssw)]) = ka0;
      *reinterpret_cast<int4*>(&Ks[strow * 64 + ((c0 + 8) ^ ssw)]) = ka1;
      *reinterpret_cast<int4*>(&Vs[strow * 64 + (c0 ^ ssw)]) = va0;
      *reinterpret_cast<int4*>(&Vs[strow * 64 + ((c0 + 8) ^ ssw)]) = va1;
    }
    __syncthreads();

    const bool rel = (j0 < spl) || (j0 + 63 >= i0 - WINDOW_ && j0 <= i0 + 15);
    if (rel) {
      // QK^T: S[16 q][64 kv] as 4 sub-tiles
      f32x4 s[4];
#pragma unroll
      for (int ks = 0; ks < 4; ks++) {
        const int krow = ks * 16 + lr;
        const int sw = (krow & 7) << 3;
        bf16x8 b0 = *reinterpret_cast<const bf16x8*>(&Ks[krow * 64 + ((lg * 8) ^ sw)]);
        bf16x8 b1 = *reinterpret_cast<const bf16x8*>(&Ks[krow * 64 + ((32 + lg * 8) ^ sw)]);
        f32x4 t = f32x4{0.f, 0.f, 0.f, 0.f};
        t = __builtin_amdgcn_mfma_f32_16x16x32_bf16(aq0, b0, t, 0, 0, 0);
        s[ks] = __builtin_amdgcn_mfma_f32_16x16x32_bf16(aq1, b1, t, 0, 0, 0);
      }

      // fused softcap+softmax with fixed max M=30 (scores bounded by softcap)
      const bool fullv = (j0 + 63 < spl) ||
                         ((j0 + 63 <= i0) && (i0 + 15 - j0 <= WINDOW_));
      if (fullv) {
#pragma unroll
        for (int r = 0; r < 4; r++) {
          const int prow = lg * 4 + r;
#pragma unroll
          for (int ks = 0; ks < 4; ks++) {
            float t = __builtin_amdgcn_exp2f(s[ks][r] * C1);
            float p = __builtin_amdgcn_exp2f(C3 * __builtin_amdgcn_rcpf(1.0f + t));
            Ps[w][prow][ks * 16 + lr] = f2bf(p);
          }
        }
      } else {
#pragma unroll
        for (int r = 0; r < 4; r++) {
          const int prow = lg * 4 + r;
          const int irow = i0 + prow;
#pragma unroll
          for (int ks = 0; ks < 4; ks++) {
            const int jc = j0 + ks * 16 + lr;
            float t = __builtin_amdgcn_exp2f(s[ks][r] * C1);
            float p = __builtin_amdgcn_exp2f(C3 * __builtin_amdgcn_rcpf(1.0f + t));
            bool valid = (jc <= irow && irow - jc <= WINDOW_) || (jc < spl);
            p = valid ? p : 0.0f;
            Ps[w][prow][ks * 16 + lr] = f2bf(p);
          }
        }
      }

      // ensure this wave's cross-lane P writes have landed in LDS
      asm volatile("s_waitcnt lgkmcnt(0)" ::: "memory");

      bf16x8 pa0 = *reinterpret_cast<const bf16x8*>(&Ps[w][lr][lg * 8]);
      bf16x8 pa1 = *reinterpret_cast<const bf16x8*>(&Ps[w][lr][32 + lg * 8]);

      // row sums via ones-MFMA (accumulates across tiles; no rescale needed)
      accl = __builtin_amdgcn_mfma_f32_16x16x32_bf16(pa0, ONES, accl, 0, 0, 0);
      accl = __builtin_amdgcn_mfma_f32_16x16x32_bf16(pa1, ONES, accl, 0, 0, 0);

#pragma unroll
      for (int nb = 0; nb < 4; nb++) {
        const int vrow = nb * 16 + lr;
        const int sw = (vrow & 7) << 3;
        bf16x8 bv0 = *reinterpret_cast<const bf16x8*>(&Vs[vrow * 64 + ((lg * 8) ^ sw)]);
        bf16x8 bv1 = *reinterpret_cast<const bf16x8*>(&Vs[vrow * 64 + ((32 + lg * 8) ^ sw)]);
        acc[nb] = __builtin_amdgcn_mfma_f32_16x16x32_bf16(pa0, bv0, acc[nb], 0, 0, 0);
        acc[nb] = __builtin_amdgcn_mfma_f32_16x16x32_bf16(pa1, bv1, acc[nb], 0, 0, 0);
      }
    }
    __syncthreads();
  }

  float rl[4];
#pragma unroll
  for (int r = 0; r < 4; r++) rl[r] = __builtin_amdgcn_rcpf(accl[r]);
#pragma unroll
  for (int nb = 0; nb < 4; nb++) {
#pragma unroll
    for (int r = 0; r < 4; r++) {
      float o = acc[nb][r] * rl[r];
      int t = i0 + lg * 4 + r;
      out[((size_t)(b * T_ + t)) * C_ + h * D_ + nb * 16 + lr] = f2bf(o);
    }
  }
}

extern "C" void kernel_launch(void* const* d_in, const int* in_sizes, int n_in,
                              void* d_out, int out_size, void* d_ws, size_t ws_size,
                              hipStream_t stream) {
  const float* x = (const float*)d_in[0];
  const int* spl = (const int*)d_in[1];
  const float* Wqkv = (const float*)d_in[2];
  const float* bqkv = (const float*)d_in[3];
  const float* Wproj = (const float*)d_in[4];
  const float* bproj = (const float*)d_in[5];
  float* out = (float*)d_out;

  char* ws = (char*)d_ws;
  unsigned short* xb = (unsigned short*)ws;       ws += (size_t)M_ * K_ * 2;        // 8 MB
  unsigned short* wqkvb = (unsigned short*)ws;    ws += (size_t)3 * C_ * K_ * 2;    // 6 MB
  unsigned short* wprojb = (unsigned short*)ws;   ws += (size_t)C_ * K_ * 2;        // 2 MB
  unsigned short* qb = (unsigned short*)ws;       ws += (size_t)M_ * C_ * 2;        // 8 MB
  unsigned short* kb = (unsigned short*)ws;       ws += (size_t)M_ * C_ * 2;        // 8 MB
  unsigned short* vtb = (unsigned short*)ws;      ws += (size_t)M_ * C_ * 2;        // 8 MB
  unsigned short* ab = (unsigned short*)ws;       ws += (size_t)M_ * C_ * 2;        // 8 MB

  {
    int n4 = (M_ * K_) / 4;
    cvt_f32_bf16<<<(n4 + 255) / 256, 256, 0, stream>>>(x, xb, n4);
  }
  {
    int n4 = (3 * C_ * K_) / 4;
    cvt_f32_bf16<<<(n4 + 255) / 256, 256, 0, stream>>>(Wqkv, wqkvb, n4);
  }
  {
    int n4 = (C_ * K_) / 4;
    cvt_f32_bf16<<<(n4 + 255) / 256, 256, 0, stream>>>(Wproj, wprojb, n4);
  }

  // QK projection: N=2048 (first 2048 rows of W_qkv)
  gemm_bt<0><<<dim3(2048 / 128, M_ / 128), 256, 0, stream>>>(
      xb, wqkvb, bqkv, qb, kb, nullptr, nullptr);

  // V projection, swapped: A = W_v (1024 rows), B = x (4096 rows) -> vt[B,H,64,T]
  gemm_bt<2><<<dim3(M_ / 128, 1024 / 128), 256, 0, stream>>>(
      wqkvb + (size_t)2048 * K_, xb, bqkv + 2048, nullptr, nullptr, vtb, nullptr);

  attn_fwd<<<dim3(1024), 256, 0, stream>>>(qb, kb, vtb, spl, ab);

  gemm_bt<1><<<dim3(C_ / 128, M_ / 128), 256, 0, stream>>>(
      ab, wprojb, bproj, nullptr, nullptr, nullptr, out);
}